// Round 11
// baseline (70.301 us; speedup 1.0000x reference)
//
#include <hip/hip_runtime.h>
#include <math.h>

// Multi-scale RoIAlign (FPN), fp32 — bin-major register-only gather, tuned for
// maximum memory-level parallelism (discriminating experiment: latency-bound
// vs line-pipe-bound).
// Block = 1 wave (64 threads) = (roi, 8 channels); grid = nroi*32; no
// __syncthreads anywhere. Lane = output bin (49/64).
// NARROW rois (bw<=4): 4 unaligned float4 tap-row loads/channel with
// channel-invariant folded 4-weight dot; 3-buffer pipeline keeps 12 loads in
// flight per wave. WIDE rois: 8 float2 loads/channel, 2-buffer pipeline.
// launch_bounds(64,7) caps VGPR at ~73 to hold >=7 waves/SIMD.

constexpr int CH = 256;
constexpr int POUT = 7;
constexpr int NSAMP = 14;           // POUT * SR
constexpr int NBIN = POUT * POUT;   // 49
constexpr int PER_ROI = CH * NBIN;  // 12544
constexpr int CPW = 8;              // channels per wave/block
constexpr int NCG = CH / CPW;       // 32 blocks per roi

struct F2 { float x, y; };
__device__ inline F2 ld2(const float* p) { F2 v; __builtin_memcpy(&v, p, 8); return v; }
struct F4 { float x, y, z, w; };
__device__ inline F4 ld4(const float* p) { F4 v; __builtin_memcpy(&v, p, 16); return v; }

__global__ __launch_bounds__(64, 7)
void roi_align_mlp_kernel(const float* __restrict__ f0,
                          const float* __restrict__ f1,
                          const float* __restrict__ f2,
                          const float* __restrict__ f3,
                          const float* __restrict__ boxes,
                          float* __restrict__ out,
                          int K)
{
    __shared__ int   s_rowoff[2 * NSAMP];          // per-tap clamped row * W
    __shared__ float s_wy0[NSAMP], s_wy1[NSAMP];   // y weights * 0.25 (validity folded)
    __shared__ int   s_xlc[NSAMP];                 // x float2 col (<= W-2)
    __shared__ float s_ex0[NSAMP], s_ex1[NSAMP];   // x weights, edge+validity folded

    const int lane = threadIdx.x;                  // block == wave
    const int roi  = blockIdx.x >> 5;              // NCG == 32
    const int cg   = blockIdx.x & (NCG - 1);
    const int b    = roi / K;

    const float bx1 = boxes[roi * 4 + 0], by1 = boxes[roi * 4 + 1];
    const float bx2 = boxes[roi * 4 + 2], by2 = boxes[roi * 4 + 3];

    const float area = (bx2 - bx1) * (by2 - by1);
    float lvlf = floorf(4.0f + log2f(sqrtf(area) / 224.0f + 1e-6f));
    lvlf = fminf(fmaxf(lvlf, 2.0f), 5.0f);
    const int lvl = (int)lvlf - 2;

    const float* feat; int H, W; float scale;
    if (lvl == 0)      { feat = f0; H = 200; W = 200; scale = 0.25f;    }
    else if (lvl == 1) { feat = f1; H = 100; W = 100; scale = 0.125f;   }
    else if (lvl == 2) { feat = f2; H = 50;  W = 50;  scale = 0.0625f;  }
    else               { feat = f3; H = 25;  W = 25;  scale = 0.03125f; }

    const float x1 = bx1 * scale, y1 = by1 * scale;
    const float rw = fmaxf(bx2 * scale - x1, 1.0f);
    const float rh = fmaxf(by2 * scale - y1, 1.0f);
    const float bw = rw * (1.0f / POUT);
    const float bh = rh * (1.0f / POUT);

    if (lane < 2 * NSAMP) {
        const bool isY = lane < NSAMP;
        const int i = isY ? lane : lane - NSAMP;
        const float dim   = isY ? (float)H : (float)W;
        const float start = isY ? y1 : x1;
        const float bsz   = isY ? bh : bw;
        const float p = start + ((float)i + 0.5f) * 0.5f * bsz;
        const float valid = (p >= -1.0f && p <= dim) ? 1.0f : 0.0f;
        const float pc = fminf(fmaxf(p, 0.0f), dim - 1.0f);
        const int q0 = (int)floorf(pc);
        const float l = pc - (float)q0;
        const float w0 = (1.0f - l) * valid;
        const float w1 = l * valid;
        if (isY) {
            const int q1 = min(q0 + 1, (int)dim - 1);
            s_rowoff[2 * i]     = q0 * W;
            s_rowoff[2 * i + 1] = q1 * W;
            s_wy0[i] = w0 * 0.25f;                 // fold sample mean
            s_wy1[i] = w1 * 0.25f;
        } else {
            // float2 at col lc covers (lc, lc+1). If q0==W-1, fold w0 onto .y.
            const bool edge = (q0 > W - 2);
            s_xlc[i] = edge ? (W - 2) : q0;
            s_ex0[i] = edge ? 0.0f : w0;
            s_ex1[i] = edge ? (w1 + w0) : w1;
        }
    }
    // Single wave: DS ops are in-order per wave; just drain lgkmcnt.
    asm volatile("s_waitcnt lgkmcnt(0)" ::: "memory");
    __builtin_amdgcn_sched_barrier(0);

    // Wave-uniform path decision: every bin's two x-samples fit a 4-col window.
    bool narrow = true;
    #pragma unroll
    for (int j = 0; j < POUT; ++j)
        narrow = narrow && (s_xlc[2 * j + 1] - s_xlc[2 * j] <= 2);

    // ---- per-lane (bin) channel-invariant state ----
    const int  lp = (lane < NBIN) ? lane : (NBIN - 1);
    const bool act = (lane < NBIN);
    const int  by = lp / POUT, bx = lp - POUT * by;

    const int ro0 = s_rowoff[4 * by + 0];
    const int ro1 = s_rowoff[4 * by + 1];
    const int ro2 = s_rowoff[4 * by + 2];
    const int ro3 = s_rowoff[4 * by + 3];
    const float wy0 = s_wy0[2 * by],     wy1 = s_wy1[2 * by];
    const float wy2 = s_wy0[2 * by + 1], wy3 = s_wy1[2 * by + 1];

    const int lc0 = s_xlc[2 * bx], lc1 = s_xlc[2 * bx + 1];
    const float e00 = s_ex0[2 * bx],     e01 = s_ex1[2 * bx];
    const float e10 = s_ex0[2 * bx + 1], e11 = s_ex1[2 * bx + 1];

    const int HW = H * W;
    const int cbase = cg * CPW;
    const float* chan0 = feat + ((size_t)b * CH + cbase) * (size_t)HW;
    const size_t obase = (size_t)roi * PER_ROI + (size_t)cbase * NBIN + lp;

    if (narrow) {
        const int base = min(lc0, W - 4);
        const int i0 = lc0 - base;          // 0..2 (>0 only at right edge)
        const int i1 = lc1 - base;          // i0..2
        const float w40 = (i0 == 0 ? e00 : 0.0f) + (i1 == 0 ? e10 : 0.0f);
        const float w41 = (i0 == 1 ? e00 : 0.0f) + (i0 == 0 ? e01 : 0.0f)
                        + (i1 == 1 ? e10 : 0.0f) + (i1 == 0 ? e11 : 0.0f);
        const float w42 = (i0 == 2 ? e00 : 0.0f) + (i0 == 1 ? e01 : 0.0f)
                        + (i1 == 2 ? e10 : 0.0f) + (i1 == 1 ? e11 : 0.0f);
        const float w43 = (i0 == 2 ? e01 : 0.0f) + (i1 == 2 ? e11 : 0.0f);

        F4 A0, A1, A2, A3, B0, B1, B2, B3, C0, C1, C2, C3;

#define LDN(S0, S1, S2, S3, c) do {                                            \
    const float* ch_ = chan0 + (size_t)(c) * HW;                               \
    S0 = ld4(ch_ + ro0 + base);                                                \
    S1 = ld4(ch_ + ro1 + base);                                                \
    S2 = ld4(ch_ + ro2 + base);                                                \
    S3 = ld4(ch_ + ro3 + base);                                                \
} while (0)

#define CPN(S0, S1, S2, S3, c) do {                                            \
    const float rv0 = S0.x * w40 + S0.y * w41 + S0.z * w42 + S0.w * w43;       \
    const float rv1 = S1.x * w40 + S1.y * w41 + S1.z * w42 + S1.w * w43;       \
    const float rv2 = S2.x * w40 + S2.y * w41 + S2.z * w42 + S2.w * w43;       \
    const float rv3 = S3.x * w40 + S3.y * w41 + S3.z * w42 + S3.w * w43;       \
    const float acc = wy0 * rv0 + wy1 * rv1 + wy2 * rv2 + wy3 * rv3;           \
    if (act) out[obase + (size_t)(c) * NBIN] = acc;                            \
} while (0)

        // 3-buffer, 2-channel-deep pipeline: 12 loads in flight.
        LDN(A0, A1, A2, A3, 0);
        LDN(B0, B1, B2, B3, 1);
        LDN(C0, C1, C2, C3, 2);
        CPN(A0, A1, A2, A3, 0); LDN(A0, A1, A2, A3, 3);
        CPN(B0, B1, B2, B3, 1); LDN(B0, B1, B2, B3, 4);
        CPN(C0, C1, C2, C3, 2); LDN(C0, C1, C2, C3, 5);
        CPN(A0, A1, A2, A3, 3); LDN(A0, A1, A2, A3, 6);
        CPN(B0, B1, B2, B3, 4); LDN(B0, B1, B2, B3, 7);
        CPN(C0, C1, C2, C3, 5);
        CPN(A0, A1, A2, A3, 6);
        CPN(B0, B1, B2, B3, 7);
#undef LDN
#undef CPN
    } else {
        // WIDE: two float2 per tap-row, 2-buffer pipeline (bounds kernel VGPR).
        F2 a0, a1, a2, a3, d0, d1, d2, d3;
        F2 p0, p1, p2, p3, q0, q1, q2, q3;

#define LDW(Sa0, Sa1, Sa2, Sa3, Sd0, Sd1, Sd2, Sd3, c) do {                    \
    const float* ch_ = chan0 + (size_t)(c) * HW;                               \
    Sa0 = ld2(ch_ + ro0 + lc0); Sd0 = ld2(ch_ + ro0 + lc1);                    \
    Sa1 = ld2(ch_ + ro1 + lc0); Sd1 = ld2(ch_ + ro1 + lc1);                    \
    Sa2 = ld2(ch_ + ro2 + lc0); Sd2 = ld2(ch_ + ro2 + lc1);                    \
    Sa3 = ld2(ch_ + ro3 + lc0); Sd3 = ld2(ch_ + ro3 + lc1);                    \
} while (0)

#define CPW_(Sa0, Sa1, Sa2, Sa3, Sd0, Sd1, Sd2, Sd3, c) do {                   \
    const float rv0 = e00 * Sa0.x + e01 * Sa0.y + e10 * Sd0.x + e11 * Sd0.y;   \
    const float rv1 = e00 * Sa1.x + e01 * Sa1.y + e10 * Sd1.x + e11 * Sd1.y;   \
    const float rv2 = e00 * Sa2.x + e01 * Sa2.y + e10 * Sd2.x + e11 * Sd2.y;   \
    const float rv3 = e00 * Sa3.x + e01 * Sa3.y + e10 * Sd3.x + e11 * Sd3.y;   \
    const float acc = wy0 * rv0 + wy1 * rv1 + wy2 * rv2 + wy3 * rv3;           \
    if (act) out[obase + (size_t)(c) * NBIN] = acc;                            \
} while (0)

        LDW(a0, a1, a2, a3, d0, d1, d2, d3, 0);
        LDW(p0, p1, p2, p3, q0, q1, q2, q3, 1);
        CPW_(a0, a1, a2, a3, d0, d1, d2, d3, 0); LDW(a0, a1, a2, a3, d0, d1, d2, d3, 2);
        CPW_(p0, p1, p2, p3, q0, q1, q2, q3, 1); LDW(p0, p1, p2, p3, q0, q1, q2, q3, 3);
        CPW_(a0, a1, a2, a3, d0, d1, d2, d3, 2); LDW(a0, a1, a2, a3, d0, d1, d2, d3, 4);
        CPW_(p0, p1, p2, p3, q0, q1, q2, q3, 3); LDW(p0, p1, p2, p3, q0, q1, q2, q3, 5);
        CPW_(a0, a1, a2, a3, d0, d1, d2, d3, 4); LDW(a0, a1, a2, a3, d0, d1, d2, d3, 6);
        CPW_(p0, p1, p2, p3, q0, q1, q2, q3, 5); LDW(p0, p1, p2, p3, q0, q1, q2, q3, 7);
        CPW_(a0, a1, a2, a3, d0, d1, d2, d3, 6);
        CPW_(p0, p1, p2, p3, q0, q1, q2, q3, 7);
#undef LDW
#undef CPW_
    }
}

extern "C" void kernel_launch(void* const* d_in, const int* in_sizes, int n_in,
                              void* d_out, int out_size, void* d_ws, size_t ws_size,
                              hipStream_t stream) {
    const float* f0    = (const float*)d_in[0];
    const float* f1    = (const float*)d_in[1];
    const float* f2    = (const float*)d_in[2];
    const float* f3    = (const float*)d_in[3];
    const float* boxes = (const float*)d_in[4];
    float* out = (float*)d_out;

    const int B    = in_sizes[0] / (256 * 200 * 200);
    const int nroi = in_sizes[4] / 4;
    const int K    = nroi / B;

    roi_align_mlp_kernel<<<nroi * NCG, 64, 0, stream>>>(f0, f1, f2, f3, boxes, out, K);
}

// Round 12
// 64.031 us; speedup vs baseline: 1.0979x; 1.0979x over previous
//
#include <hip/hip_runtime.h>
#include <math.h>

// Multi-scale RoIAlign (FPN), fp32 — bin-major register-only gather.
// Block = (roi, 16 channels), 2 waves x 8 channels. Lane = output bin (49/64).
// Per channel per lane: 4 tap-rows; NARROW rois (x-taps of both x-samples fit
// in 4 consecutive cols, i.e. bw<=4 — all level-1 + most level-0 rois): one
// unaligned float4 per row + channel-invariant 4-weight dot (both x-interps
// folded) -> 4 loads + 1 store = 5 VMEM instrs, ZERO LDS in the loop.
// WIDE rois: 2 float2 per row (8 loads), same epilogue. Single dispatch,
// block-uniform branch. Register double-buffer across the 8-channel loop.
//
// R11 post-mortem: this configuration sits on the structural wall —
// ~70 distinct cache lines per (roi,channel) task: TA line-processing
// (~30us) + compulsory L2->L1 refill (~1.17GB @ 34.5TB/s ~ 34us). Store
// batching (R9), prologue amortization (R10), and 2.4x MLP (R11) were all
// neutral-to-negative; this exact kernel measured best (64.08us wall).

constexpr int CH = 256;
constexpr int POUT = 7;
constexpr int NSAMP = 14;           // POUT * SR
constexpr int NBIN = POUT * POUT;   // 49
constexpr int PER_ROI = CH * NBIN;  // 12544
constexpr int NWAVE = 2;
constexpr int CPW = 8;              // channels per wave
constexpr int CPB = NWAVE * CPW;    // 16 channels per block
constexpr int NCG = CH / CPB;       // 16 blocks per roi

struct F2 { float x, y; };
__device__ inline F2 ld2(const float* p) { F2 v; __builtin_memcpy(&v, p, 8); return v; }
struct F4 { float x, y, z, w; };
__device__ inline F4 ld4(const float* p) { F4 v; __builtin_memcpy(&v, p, 16); return v; }

__global__ __launch_bounds__(128)
void roi_align_bin_kernel(const float* __restrict__ f0,
                          const float* __restrict__ f1,
                          const float* __restrict__ f2,
                          const float* __restrict__ f3,
                          const float* __restrict__ boxes,
                          float* __restrict__ out,
                          int K)
{
    __shared__ int   s_rowoff[2 * NSAMP];          // per-tap clamped row * W
    __shared__ float s_wy0[NSAMP], s_wy1[NSAMP];   // y weights (validity folded)
    __shared__ int   s_xlc[NSAMP];                 // x float2 col (<= W-2), edge-folded
    __shared__ float s_ex0[NSAMP], s_ex1[NSAMP];   // x weights, edge+validity folded

    const int tid  = threadIdx.x;
    const int wave = tid >> 6;
    const int lane = tid & 63;
    const int roi  = blockIdx.x >> 4;              // NCG == 16
    const int cg   = blockIdx.x & (NCG - 1);
    const int b    = roi / K;

    const float bx1 = boxes[roi * 4 + 0], by1 = boxes[roi * 4 + 1];
    const float bx2 = boxes[roi * 4 + 2], by2 = boxes[roi * 4 + 3];

    const float area = (bx2 - bx1) * (by2 - by1);
    float lvlf = floorf(4.0f + log2f(sqrtf(area) / 224.0f + 1e-6f));
    lvlf = fminf(fmaxf(lvlf, 2.0f), 5.0f);
    const int lvl = (int)lvlf - 2;

    const float* feat; int H, W; float scale;
    if (lvl == 0)      { feat = f0; H = 200; W = 200; scale = 0.25f;    }
    else if (lvl == 1) { feat = f1; H = 100; W = 100; scale = 0.125f;   }
    else if (lvl == 2) { feat = f2; H = 50;  W = 50;  scale = 0.0625f;  }
    else               { feat = f3; H = 25;  W = 25;  scale = 0.03125f; }

    const float x1 = bx1 * scale, y1 = by1 * scale;
    const float rw = fmaxf(bx2 * scale - x1, 1.0f);
    const float rh = fmaxf(by2 * scale - y1, 1.0f);
    const float bw = rw * (1.0f / POUT);
    const float bh = rh * (1.0f / POUT);

    if (tid < 2 * NSAMP) {
        const bool isY = tid < NSAMP;
        const int i = isY ? tid : tid - NSAMP;
        const float dim   = isY ? (float)H : (float)W;
        const float start = isY ? y1 : x1;
        const float bsz   = isY ? bh : bw;
        const float p = start + ((float)i + 0.5f) * 0.5f * bsz;
        const float valid = (p >= -1.0f && p <= dim) ? 1.0f : 0.0f;
        const float pc = fminf(fmaxf(p, 0.0f), dim - 1.0f);
        const int q0 = (int)floorf(pc);
        const float l = pc - (float)q0;
        const float w0 = (1.0f - l) * valid;
        const float w1 = l * valid;
        if (isY) {
            const int q1 = min(q0 + 1, (int)dim - 1);
            s_rowoff[2 * i]     = q0 * W;
            s_rowoff[2 * i + 1] = q1 * W;
            s_wy0[i] = w0;
            s_wy1[i] = w1;
        } else {
            // float2 at col lc covers (lc, lc+1). If q0==W-1, fold w0 onto .y.
            const bool edge = (q0 > W - 2);
            s_xlc[i] = edge ? (W - 2) : q0;
            s_ex0[i] = edge ? 0.0f : w0;
            s_ex1[i] = edge ? (w1 + w0) : w1;
        }
    }
    __syncthreads();

    // Block-uniform path decision: both x-samples of every bin must fit a
    // 4-col window (lc spacing <= 2).
    bool narrow = true;
    #pragma unroll
    for (int j = 0; j < POUT; ++j)
        narrow = narrow && (s_xlc[2 * j + 1] - s_xlc[2 * j] <= 2);

    // ---- per-lane (bin) channel-invariant state ----
    const int  lp = (lane < NBIN) ? lane : (NBIN - 1);
    const bool act = (lane < NBIN);
    const int  by = lp / POUT, bx = lp - POUT * by;

    const int ro0 = s_rowoff[4 * by + 0];   // sample 2by   tap rows
    const int ro1 = s_rowoff[4 * by + 1];
    const int ro2 = s_rowoff[4 * by + 2];   // sample 2by+1 tap rows
    const int ro3 = s_rowoff[4 * by + 3];
    const float wy0 = s_wy0[2 * by],     wy1 = s_wy1[2 * by];
    const float wy2 = s_wy0[2 * by + 1], wy3 = s_wy1[2 * by + 1];

    const int lc0 = s_xlc[2 * bx], lc1 = s_xlc[2 * bx + 1];
    const float e00 = s_ex0[2 * bx],     e01 = s_ex1[2 * bx];
    const float e10 = s_ex0[2 * bx + 1], e11 = s_ex1[2 * bx + 1];

    const int HW = H * W;
    const int cbase = cg * CPB + wave * CPW;
    const float* chan0 = feat + ((size_t)b * CH + cbase) * (size_t)HW;
    const size_t obase = (size_t)roi * PER_ROI + (size_t)cbase * NBIN + lp;

    if (narrow) {
        // float4 window [base, base+3] covers taps (lc0,lc0+1,lc1,lc1+1).
        const int base = min(lc0, W - 4);
        const int i0 = lc0 - base;          // 0..2 (>0 only at right edge)
        const int i1 = lc1 - base;          // i0..2
        // Fold both x-interps into one 4-weight vector (channel-invariant).
        const float w40 = (i0 == 0 ? e00 : 0.0f) + (i1 == 0 ? e10 : 0.0f);
        const float w41 = (i0 == 1 ? e00 : 0.0f) + (i0 == 0 ? e01 : 0.0f)
                        + (i1 == 1 ? e10 : 0.0f) + (i1 == 0 ? e11 : 0.0f);
        const float w42 = (i0 == 2 ? e00 : 0.0f) + (i0 == 1 ? e01 : 0.0f)
                        + (i1 == 2 ? e10 : 0.0f) + (i1 == 1 ? e11 : 0.0f);
        const float w43 = (i0 == 2 ? e01 : 0.0f) + (i1 == 2 ? e11 : 0.0f);

        F4 v0 = ld4(chan0 + ro0 + base);
        F4 v1 = ld4(chan0 + ro1 + base);
        F4 v2 = ld4(chan0 + ro2 + base);
        F4 v3 = ld4(chan0 + ro3 + base);

        #pragma unroll
        for (int c = 0; c < CPW; ++c) {
            F4 n0, n1, n2, n3;
            if (c + 1 < CPW) {
                const float* ch = chan0 + (size_t)(c + 1) * HW;
                n0 = ld4(ch + ro0 + base);
                n1 = ld4(ch + ro1 + base);
                n2 = ld4(ch + ro2 + base);
                n3 = ld4(ch + ro3 + base);
            }
            const float rv0 = v0.x * w40 + v0.y * w41 + v0.z * w42 + v0.w * w43;
            const float rv1 = v1.x * w40 + v1.y * w41 + v1.z * w42 + v1.w * w43;
            const float rv2 = v2.x * w40 + v2.y * w41 + v2.z * w42 + v2.w * w43;
            const float rv3 = v3.x * w40 + v3.y * w41 + v3.z * w42 + v3.w * w43;
            const float acc = wy0 * rv0 + wy1 * rv1 + wy2 * rv2 + wy3 * rv3;
            if (act) out[obase + (size_t)c * NBIN] = acc * 0.25f;
            v0 = n0; v1 = n1; v2 = n2; v3 = n3;
        }
    } else {
        // WIDE: two float2 per tap-row (x-taps far apart).
        F2 a0 = ld2(chan0 + ro0 + lc0), d0 = ld2(chan0 + ro0 + lc1);
        F2 a1 = ld2(chan0 + ro1 + lc0), d1 = ld2(chan0 + ro1 + lc1);
        F2 a2 = ld2(chan0 + ro2 + lc0), d2 = ld2(chan0 + ro2 + lc1);
        F2 a3 = ld2(chan0 + ro3 + lc0), d3 = ld2(chan0 + ro3 + lc1);

        #pragma unroll
        for (int c = 0; c < CPW; ++c) {
            F2 na0, na1, na2, na3, nd0, nd1, nd2, nd3;
            if (c + 1 < CPW) {
                const float* ch = chan0 + (size_t)(c + 1) * HW;
                na0 = ld2(ch + ro0 + lc0); nd0 = ld2(ch + ro0 + lc1);
                na1 = ld2(ch + ro1 + lc0); nd1 = ld2(ch + ro1 + lc1);
                na2 = ld2(ch + ro2 + lc0); nd2 = ld2(ch + ro2 + lc1);
                na3 = ld2(ch + ro3 + lc0); nd3 = ld2(ch + ro3 + lc1);
            }
            const float rv0 = e00 * a0.x + e01 * a0.y + e10 * d0.x + e11 * d0.y;
            const float rv1 = e00 * a1.x + e01 * a1.y + e10 * d1.x + e11 * d1.y;
            const float rv2 = e00 * a2.x + e01 * a2.y + e10 * d2.x + e11 * d2.y;
            const float rv3 = e00 * a3.x + e01 * a3.y + e10 * d3.x + e11 * d3.y;
            const float acc = wy0 * rv0 + wy1 * rv1 + wy2 * rv2 + wy3 * rv3;
            if (act) out[obase + (size_t)c * NBIN] = acc * 0.25f;
            a0 = na0; a1 = na1; a2 = na2; a3 = na3;
            d0 = nd0; d1 = nd1; d2 = nd2; d3 = nd3;
        }
    }
}

extern "C" void kernel_launch(void* const* d_in, const int* in_sizes, int n_in,
                              void* d_out, int out_size, void* d_ws, size_t ws_size,
                              hipStream_t stream) {
    const float* f0    = (const float*)d_in[0];
    const float* f1    = (const float*)d_in[1];
    const float* f2    = (const float*)d_in[2];
    const float* f3    = (const float*)d_in[3];
    const float* boxes = (const float*)d_in[4];
    float* out = (float*)d_out;

    const int B    = in_sizes[0] / (256 * 200 * 200);
    const int nroi = in_sizes[4] / 4;
    const int K    = nroi / B;

    roi_align_bin_kernel<<<nroi * NCG, 128, 0, stream>>>(f0, f1, f2, f3, boxes, out, K);
}